// Round 6
// baseline (98.774 us; speedup 1.0000x reference)
//
#include <hip/hip_runtime.h>
#include <math.h>

#define CHUNK 256
#define CH 128
#define LPP 32            // lanes per point
#define PPB 8             // points per 256-thread block

typedef float f32x4 __attribute__((ext_vector_type(4)));
typedef unsigned int u32x2 __attribute__((ext_vector_type(2)));
typedef unsigned int u32x4 __attribute__((ext_vector_type(4)));
typedef unsigned short u16x4 __attribute__((ext_vector_type(4)));

// ---------------- scan kernels: starts[p] = exclusive_sum(nn_count)[p] ----

__global__ void k1_partial(const int* __restrict__ cnt, int* __restrict__ partial, int n) {
    int i = blockIdx.x * CHUNK + threadIdx.x;
    int v = (i < n) ? cnt[i] : 0;
    __shared__ int sm[CHUNK];
    sm[threadIdx.x] = v;
    __syncthreads();
    for (int off = CHUNK / 2; off > 0; off >>= 1) {
        if (threadIdx.x < off) sm[threadIdx.x] += sm[threadIdx.x + off];
        __syncthreads();
    }
    if (threadIdx.x == 0) partial[blockIdx.x] = sm[0];
}

// single block exclusive scan of partials (nb <= 512)
__global__ void k2_scan(int* __restrict__ partial, int nb) {
    __shared__ int sm[512];
    int v = (threadIdx.x < nb) ? partial[threadIdx.x] : 0;
    sm[threadIdx.x] = v;
    __syncthreads();
    for (int off = 1; off < 512; off <<= 1) {
        int t = (threadIdx.x >= off) ? sm[threadIdx.x - off] : 0;
        __syncthreads();
        sm[threadIdx.x] += t;
        __syncthreads();
    }
    if (threadIdx.x < nb) partial[threadIdx.x] = sm[threadIdx.x] - v;  // exclusive
}

__global__ void k3_starts(const int* __restrict__ cnt, const int* __restrict__ partial,
                          int* __restrict__ starts, int n) {
    int i = blockIdx.x * CHUNK + threadIdx.x;
    int v = (i < n) ? cnt[i] : 0;
    __shared__ int sm[CHUNK];
    sm[threadIdx.x] = v;
    __syncthreads();
    for (int off = 1; off < CHUNK; off <<= 1) {
        int t = (threadIdx.x >= off) ? sm[threadIdx.x - off] : 0;
        __syncthreads();
        sm[threadIdx.x] += t;
        __syncthreads();
    }
    if (i < n) starts[i] = partial[blockIdx.x] + sm[threadIdx.x] - v;
}

// ---------------- fp32 -> monotone-u16-key conversion ---------------------
// key = bf16RNE(x) mapped order-preservingly to u16:
//   h>=0x8000 (neg): k = ~h ; else k = h | 0x8000.  Bijective & monotone.

__device__ inline unsigned int rb(unsigned int b) {
    return (b + 0x7FFFu + ((b >> 16) & 1u)) >> 16;   // RNE bf16 bits
}

__device__ inline unsigned int key2(unsigned int h2) {
    // transform two packed bf16 halves to keys (per-half sign flip)
    unsigned int s = (h2 >> 15) & 0x00010001u;       // sign bits per half
    return h2 ^ (0x80008000u | ((s << 15) - s));     // ^0x8000 (pos) / ^0xFFFF (neg)
}

__global__ void conv_keys(const u32x4* __restrict__ in, u32x4* __restrict__ out, int n8) {
    int i = blockIdx.x * 256 + threadIdx.x;
    if (i >= n8) return;
    u32x4 a = __builtin_nontemporal_load(&in[2 * i]);
    u32x4 b = __builtin_nontemporal_load(&in[2 * i + 1]);
    u32x4 o;
    o.x = key2(rb(a.x) | (rb(a.y) << 16));
    o.y = key2(rb(a.z) | (rb(a.w) << 16));
    o.z = key2(rb(b.x) | (rb(b.y) << 16));
    o.w = key2(rb(b.z) | (rb(b.w) << 16));
    out[i] = o;
}

// ---------------- pooling kernels -----------------------------------------

__device__ inline u16x4 kmax(u16x4 a, u16x4 b) {
    return __builtin_elementwise_max(a, b);          // v_pk_max_u16 x2
}

// key gather path: 32 lanes/point, 8 B/lane (256 B rows), integer max
__global__ __launch_bounds__(256, 8)
void pool_keys(const u16x4* __restrict__ inp2,
               const int* __restrict__ starts,
               const int* __restrict__ cnt,
               const int* __restrict__ idx,
               f32x4* __restrict__ out4, int mp) {
    int p = blockIdx.x * PPB + (threadIdx.x >> 5);
    int lane = threadIdx.x & 31;
    if (p >= mp) return;
    int s = starts[p];
    int n = cnt[p];
    int myidx = (lane < n) ? idx[s + lane] : 0;

    u16x4 m0 = {0, 0, 0, 0};
    u16x4 m1 = m0;
    int j = 0;
    for (; j + 8 <= n; j += 8) {
        int r0 = __shfl(myidx, j,     32);
        int r1 = __shfl(myidx, j + 1, 32);
        int r2 = __shfl(myidx, j + 2, 32);
        int r3 = __shfl(myidx, j + 3, 32);
        int r4 = __shfl(myidx, j + 4, 32);
        int r5 = __shfl(myidx, j + 5, 32);
        int r6 = __shfl(myidx, j + 6, 32);
        int r7 = __shfl(myidx, j + 7, 32);
        u16x4 a = inp2[r0 * 32 + lane];
        u16x4 b = inp2[r1 * 32 + lane];
        u16x4 c = inp2[r2 * 32 + lane];
        u16x4 d = inp2[r3 * 32 + lane];
        u16x4 e = inp2[r4 * 32 + lane];
        u16x4 f = inp2[r5 * 32 + lane];
        u16x4 g = inp2[r6 * 32 + lane];
        u16x4 h = inp2[r7 * 32 + lane];
        m0 = kmax(m0, kmax(kmax(a, b), kmax(c, d)));
        m1 = kmax(m1, kmax(kmax(e, f), kmax(g, h)));
    }
    if (j + 4 <= n) {
        int r0 = __shfl(myidx, j,     32);
        int r1 = __shfl(myidx, j + 1, 32);
        int r2 = __shfl(myidx, j + 2, 32);
        int r3 = __shfl(myidx, j + 3, 32);
        u16x4 a = inp2[r0 * 32 + lane];
        u16x4 b = inp2[r1 * 32 + lane];
        u16x4 c = inp2[r2 * 32 + lane];
        u16x4 d = inp2[r3 * 32 + lane];
        m0 = kmax(m0, kmax(kmax(a, b), kmax(c, d)));
        j += 4;
    }
    for (; j < n; ++j) {
        int r = __shfl(myidx, j, 32);
        m1 = kmax(m1, inp2[r * 32 + lane]);
    }
    u16x4 m = kmax(m0, m1);

    // inverse transform: keys -> bf16 bits -> fp32
    union { u16x4 k; u32x2 w; } u;
    u.k = m;
    unsigned int s0 = (u.w.x >> 15) & 0x00010001u;
    unsigned int s1 = (u.w.y >> 15) & 0x00010001u;
    unsigned int w0 = u.w.x ^ (0xFFFFFFFFu ^ ((s0 << 15) - s0));
    unsigned int w1 = u.w.y ^ (0xFFFFFFFFu ^ ((s1 << 15) - s1));
    union { unsigned int b[4]; f32x4 f; } o;
    o.b[0] = w0 << 16;
    o.b[1] = w0 & 0xFFFF0000u;
    o.b[2] = w1 << 16;
    o.b[3] = w1 & 0xFFFF0000u;
    __builtin_nontemporal_store(o.f, &out4[p * LPP + lane]);
}

// fp32 fallback (used only if ws_size can't hold the key copy)
__global__ __launch_bounds__(256, 8)
void pool_fp32(const f32x4* __restrict__ inp4,
               const int* __restrict__ starts,
               const int* __restrict__ cnt,
               const int* __restrict__ idx,
               f32x4* __restrict__ out4, int mp) {
    int p = blockIdx.x * PPB + (threadIdx.x >> 5);
    int lane = threadIdx.x & 31;
    if (p >= mp) return;
    int s = starts[p];
    int n = cnt[p];
    int myidx = (lane < n) ? idx[s + lane] : 0;
    f32x4 m0 = {-INFINITY, -INFINITY, -INFINITY, -INFINITY};
    int j = 0;
    for (; j < n; ++j) {
        int r = __shfl(myidx, j, 32);
        f32x4 a = inp4[r * LPP + lane];
        m0.x = fmaxf(m0.x, a.x);
        m0.y = fmaxf(m0.y, a.y);
        m0.z = fmaxf(m0.z, a.z);
        m0.w = fmaxf(m0.w, a.w);
    }
    __builtin_nontemporal_store(m0, &out4[p * LPP + lane]);
}

extern "C" void kernel_launch(void* const* d_in, const int* in_sizes, int n_in,
                              void* d_out, int out_size, void* d_ws, size_t ws_size,
                              hipStream_t stream) {
    const float* inp = (const float*)d_in[0];   // [N_IN, 128] fp32
    const int* cnt   = (const int*)d_in[1];     // [MP]
    const int* idx   = (const int*)d_in[2];     // [TOTAL]
    float* out       = (float*)d_out;           // [MP, 128] fp32

    int mp     = in_sizes[1];
    int n_elem = in_sizes[0];                   // N_IN * 128
    int nb     = (mp + CHUNK - 1) / CHUNK;      // <= 512 required by k2

    size_t key_bytes = (size_t)n_elem * 2;      // u16 key copy of inputs
    size_t need      = key_bytes + (size_t)(mp + nb) * 4 + 256;
    bool use_keys    = (ws_size >= need);

    int* starts;
    int* partial;
    unsigned short* keys = nullptr;
    if (use_keys) {
        keys    = (unsigned short*)d_ws;
        starts  = (int*)((char*)d_ws + key_bytes);
        partial = starts + mp;
    } else {
        starts  = (int*)d_ws;
        partial = starts + mp;
    }

    if (use_keys) {
        int n8 = n_elem / 8;
        conv_keys<<<(n8 + 255) / 256, 256, 0, stream>>>(
            (const u32x4*)inp, (u32x4*)keys, n8);
    }

    k1_partial<<<nb, CHUNK, 0, stream>>>(cnt, partial, mp);
    k2_scan<<<1, 512, 0, stream>>>(partial, nb);
    k3_starts<<<nb, CHUNK, 0, stream>>>(cnt, partial, starts, mp);

    int pool_blocks = (mp + PPB - 1) / PPB;
    if (use_keys) {
        pool_keys<<<pool_blocks, PPB * 32, 0, stream>>>(
            (const u16x4*)keys, starts, cnt, idx, (f32x4*)out, mp);
    } else {
        pool_fp32<<<pool_blocks, PPB * 32, 0, stream>>>(
            (const f32x4*)inp, starts, cnt, idx, (f32x4*)out, mp);
    }
}